// Round 1
// baseline (440.686 us; speedup 1.0000x reference)
//
#include <hip/hip_runtime.h>

// Problem constants
#define T_ 64
#define P_ 144          // 12*12 windows per frame
#define NPAIR 9216      // T_*P_
#define C_ 1024
#define MID_ 256

#define MP 16           // pairs per fused block
#define PST 1032        // bf16 pooled LDS row stride (padded)
#define UST 1028        // f32 u LDS row stride (padded)

typedef __attribute__((ext_vector_type(4))) float f32x4;
typedef __attribute__((ext_vector_type(8))) __bf16 bf16x8;
typedef __attribute__((ext_vector_type(4))) __bf16 bf16x4;

// ---------------------------------------------------------------------------
// shared MFMA tile step for the H GEMM (128x128, BK=32, 4 waves 2x2, 4x4 frags)
__device__ __forceinline__ void mfma_tile(const __bf16* As, const __bf16* Bs,
                                          int wm, int wn, int quad, int lr,
                                          f32x4 acc[4][4]) {
  bf16x8 a[4], b[4];
  const bf16x8* Ap = (const bf16x8*)As;
  const bf16x8* Bp = (const bf16x8*)Bs;
#pragma unroll
  for (int i = 0; i < 4; ++i) {
    a[i] = Ap[(wm * 64 + i * 16 + lr) * 4 + quad];
    b[i] = Bp[(wn * 64 + i * 16 + lr) * 4 + quad];
  }
#pragma unroll
  for (int mi = 0; mi < 4; ++mi)
#pragma unroll
    for (int ni = 0; ni < 4; ++ni)
      acc[mi][ni] = __builtin_amdgcn_mfma_f32_16x16x32_bf16(
          a[mi], b[ni], acc[mi][ni], 0, 0, 0);
}

// ---------------------------------------------------------------------------
// prep: weights-only precompute.
//   blocks [0, 64):   H = Wk @ Wq^T  [1024x1024] bf16 (128x128 tiles, K=256)
//   blocks [64, 68):  kb = Wk @ bq   [1024] fp32
__global__ __launch_bounds__(256) void prep_kernel(
    const float* __restrict__ Wq, const float* __restrict__ bq,
    const float* __restrict__ Wk, __bf16* __restrict__ H,
    float* __restrict__ kb) {
  __shared__ __align__(16) __bf16 As[128 * 32];
  __shared__ __align__(16) __bf16 Bs[128 * 32];
  const int bid = blockIdx.x;
  const int tid = threadIdx.x;
  if (bid < 64) {
    // H[m][n] = sum_j Wk[m][j] * Wq[n][j], m,n in 1024, j in 256
    const int mt = bid >> 3, nt = bid & 7;
    const int lane = tid & 63;
    const int wv = tid >> 6;
    const int quad = lane >> 4, lr = lane & 15;
    const int wm = wv >> 1, wn = wv & 1;
    const int r0 = tid >> 2, p0 = tid & 3;
    const float* ga0 = Wk + (size_t)(mt * 128 + r0) * MID_ + p0 * 8;
    const float* ga1 = ga0 + (size_t)64 * MID_;
    const float* gb0 = Wq + (size_t)(nt * 128 + r0) * MID_ + p0 * 8;
    const float* gb1 = gb0 + (size_t)64 * MID_;
    f32x4 acc[4][4] = {};
    for (int it = 0; it < 8; ++it) {
      const f32x4 a0 = *(const f32x4*)ga0, a1 = *(const f32x4*)(ga0 + 4);
      const f32x4 a2 = *(const f32x4*)ga1, a3 = *(const f32x4*)(ga1 + 4);
      const f32x4 b0 = *(const f32x4*)gb0, b1 = *(const f32x4*)(gb0 + 4);
      const f32x4 b2 = *(const f32x4*)gb1, b3 = *(const f32x4*)(gb1 + 4);
      ga0 += 32; ga1 += 32; gb0 += 32; gb1 += 32;
      bf16x8 ca0, ca1, cb0, cb1;
#pragma unroll
      for (int j = 0; j < 4; ++j) {
        ca0[j] = (__bf16)a0[j]; ca0[4 + j] = (__bf16)a1[j];
        ca1[j] = (__bf16)a2[j]; ca1[4 + j] = (__bf16)a3[j];
        cb0[j] = (__bf16)b0[j]; cb0[4 + j] = (__bf16)b1[j];
        cb1[j] = (__bf16)b2[j]; cb1[4 + j] = (__bf16)b3[j];
      }
      *(bf16x8*)(As + (size_t)tid * 8) = ca0;
      *(bf16x8*)(As + (size_t)(tid + 256) * 8) = ca1;
      *(bf16x8*)(Bs + (size_t)tid * 8) = cb0;
      *(bf16x8*)(Bs + (size_t)(tid + 256) * 8) = cb1;
      __syncthreads();
      mfma_tile(As, Bs, wm, wn, quad, lr, acc);
      __syncthreads();
    }
    const int colb = nt * 128 + wn * 64;
    const int rowb = mt * 128 + wm * 64 + quad * 4;
#pragma unroll
    for (int ni = 0; ni < 4; ++ni) {
      const int col = colb + ni * 16 + lr;
#pragma unroll
      for (int mi = 0; mi < 4; ++mi) {
        const int row = rowb + mi * 16;
#pragma unroll
        for (int r = 0; r < 4; ++r)
          H[(size_t)(row + r) * C_ + col] = (__bf16)acc[mi][ni][r];
      }
    }
  } else {
    __shared__ float bqs[256];
    bqs[tid] = bq[tid];
    __syncthreads();
    const int n = (bid - 64) * 256 + tid;
    const float* row = Wk + (size_t)n * MID_;
    float s = 0.f;
#pragma unroll 4
    for (int j = 0; j < 256; ++j) s += row[j] * bqs[j];
    kb[n] = s;
  }
}

// ---------------------------------------------------------------------------
// fused: per 16-pair tile (576 blocks x 512 threads, 8 waves):
//   A: pool 2x2 windows from img -> bf16 LDS A-tile (padded), stage kb
//   B: u = pooled @ H^T   (M=16, N=1024 split 8 waves x 128 cols, K=1024;
//      B-frags stream global->reg from L2-resident H; NO barriers in K-loop)
//   C: u (fp32) + kb -> LDS (overwrites pooled region after barrier)
//   D: logits u.v_w, softmax over 4 windows, out = pooled + sum a_w v_w
__global__ __launch_bounds__(512, 4) void fused_kernel(
    const __bf16* __restrict__ H, const float* __restrict__ kb,
    const float* __restrict__ img, float* __restrict__ out) {
  __shared__ __align__(16) char ubuf[MP * UST * 4];  // 65792 B union buffer
  __shared__ float kbs[C_];
  __bf16* pool_s = (__bf16*)ubuf;  // [MP][PST] bf16 (phases A,B)
  float* u_s = (float*)ubuf;       // [MP][UST] fp32 (phases C,D)

  const int tid = threadIdx.x;
  const int bid = blockIdx.x;
  const int lane = tid & 63;
  const int wv = tid >> 6;              // 0..7
  const int quad = lane >> 4, lr = lane & 15;

  // pair mapping (used in phases A and D): 32 threads per pair
  const int p = tid >> 5;               // 0..15
  const int lp = tid & 31;
  const int gp = bid * MP + p;
  const int t = gp / P_;
  const int pp = gp - t * P_;
  const int wy = pp / 12, wx = pp - wy * 12;
  const float* base = img + ((size_t)t * 576 + 48 * wy + 2 * wx) * C_;

  // ---- Phase A: pool windows -> LDS bf16, stage kb -------------------------
#pragma unroll
  for (int j = 0; j < 8; ++j) {
    const int c = lp * 4 + j * 128;
    f32x4 s = *(const f32x4*)(base + c);
    s += *(const f32x4*)(base + C_ + c);
    s += *(const f32x4*)(base + 24 * C_ + c);
    s += *(const f32x4*)(base + 25 * C_ + c);
    s *= 0.25f;
    bf16x4 pv;
#pragma unroll
    for (int q = 0; q < 4; ++q) pv[q] = (__bf16)s[q];
    *(bf16x4*)(pool_s + p * PST + c) = pv;
  }
  if (tid < 256) *(f32x4*)(kbs + tid * 4) = *(const f32x4*)(kb + tid * 4);
  __syncthreads();

  // ---- Phase B: barrier-free GEMM, u = pooled @ H^T ------------------------
  f32x4 acc[8] = {};
  const __bf16* ap = pool_s + lr * PST + quad * 8;
  const __bf16* hp[8];
#pragma unroll
  for (int j = 0; j < 8; ++j)
    hp[j] = H + (size_t)(wv * 128 + j * 16 + lr) * C_ + quad * 8;
  for (int it = 0; it < 32; ++it) {
    const bf16x8 a = *(const bf16x8*)(ap + it * 32);
    bf16x8 b[8];
#pragma unroll
    for (int j = 0; j < 8; ++j) b[j] = *(const bf16x8*)(hp[j] + it * 32);
#pragma unroll
    for (int j = 0; j < 8; ++j)
      acc[j] = __builtin_amdgcn_mfma_f32_16x16x32_bf16(a, b[j], acc[j], 0, 0, 0);
  }
  __syncthreads();  // all A-tile reads done before overwrite

  // ---- Phase C: u (fp32, +kb) into LDS ------------------------------------
#pragma unroll
  for (int j = 0; j < 8; ++j) {
    const int col = wv * 128 + j * 16 + lr;
    const float kv = kbs[col];
#pragma unroll
    for (int r = 0; r < 4; ++r)
      u_s[(quad * 4 + r) * UST + col] = acc[j][r] + kv;
  }
  __syncthreads();

  // ---- Phase D: logits + softmax + output (32 lanes per pair) -------------
  float pd0 = 0.f, pd1 = 0.f, pd2 = 0.f, pd3 = 0.f;
  for (int j = 0; j < 8; ++j) {
    const int c = lp * 4 + j * 128;
    const f32x4 u4 = *(const f32x4*)(u_s + p * UST + c);
    const f32x4 v0 = *(const f32x4*)(base + c);
    const f32x4 v1 = *(const f32x4*)(base + C_ + c);
    const f32x4 v2 = *(const f32x4*)(base + 24 * C_ + c);
    const f32x4 v3 = *(const f32x4*)(base + 25 * C_ + c);
#pragma unroll
    for (int q = 0; q < 4; ++q) {
      pd0 += u4[q] * v0[q];
      pd1 += u4[q] * v1[q];
      pd2 += u4[q] * v2[q];
      pd3 += u4[q] * v3[q];
    }
  }
#pragma unroll
  for (int m = 16; m >= 1; m >>= 1) {
    pd0 += __shfl_xor(pd0, m, 32);
    pd1 += __shfl_xor(pd1, m, 32);
    pd2 += __shfl_xor(pd2, m, 32);
    pd3 += __shfl_xor(pd3, m, 32);
  }
  const float l0 = pd0 * 0.0625f, l1 = pd1 * 0.0625f;
  const float l2 = pd2 * 0.0625f, l3 = pd3 * 0.0625f;
  const float mx = fmaxf(fmaxf(l0, l1), fmaxf(l2, l3));
  const float e0 = __expf(l0 - mx), e1 = __expf(l1 - mx);
  const float e2 = __expf(l2 - mx), e3 = __expf(l3 - mx);
  const float inv = 1.f / (e0 + e1 + e2 + e3);
  const float a0 = e0 * inv, a1 = e1 * inv;
  const float a2 = e2 * inv, a3 = e3 * inv;
  float* op = out + (size_t)gp * C_;
  for (int j = 0; j < 8; ++j) {
    const int c = lp * 4 + j * 128;
    const f32x4 v0 = *(const f32x4*)(base + c);
    const f32x4 v1 = *(const f32x4*)(base + C_ + c);
    const f32x4 v2 = *(const f32x4*)(base + 24 * C_ + c);
    const f32x4 v3 = *(const f32x4*)(base + 25 * C_ + c);
    f32x4 o = (v0 + v1 + v2 + v3) * 0.25f;
    o += a0 * v0 + a1 * v1 + a2 * v2 + a3 * v3;
    *(f32x4*)(op + c) = o;
  }
}

// ---------------------------------------------------------------------------
extern "C" void kernel_launch(void* const* d_in, const int* in_sizes, int n_in,
                              void* d_out, int out_size, void* d_ws,
                              size_t ws_size, hipStream_t stream) {
  const float* img = (const float*)d_in[0];
  const float* Wq = (const float*)d_in[1];
  const float* bq = (const float*)d_in[2];
  const float* Wk = (const float*)d_in[3];
  const float* bk = (const float*)d_in[4];  // constant under softmax -> unused
  (void)bk;
  float* out = (float*)d_out;

  // workspace layout (~2.1 MB)
  char* ws = (char*)d_ws;
  __bf16* H = (__bf16*)ws;                 // 1024*1024*2 = 2,097,152
  float* kb = (float*)(ws + 2097152);      // 1024*4      =     4,096

  // 1) H = Wk@Wq^T (bf16), kb = Wk@bq   (weights only, tiny)
  prep_kernel<<<68, 256, 0, stream>>>(Wq, bq, Wk, H, kb);
  // 2) fully fused: pool -> u = pooled@H^T + kb -> softmax -> output
  fused_kernel<<<NPAIR / MP, 512, 0, stream>>>(H, kb, img, out);
}

// Round 2
// 400.645 us; speedup vs baseline: 1.0999x; 1.0999x over previous
//
#include <hip/hip_runtime.h>

// Problem constants
#define T_ 64
#define P_ 144          // 12*12 windows per frame
#define NPAIR 9216      // T_*P_
#define C_ 1024
#define MID_ 256

#define MP 32           // pairs per fused block
#define PST 1032        // bf16 pooled LDS row stride (padded, x16B aligned)
#define UST 1036        // f32 u LDS row stride (padded: 4*UST%128=16 -> <=2-way)

typedef __attribute__((ext_vector_type(4))) float f32x4;
typedef __attribute__((ext_vector_type(8))) __bf16 bf16x8;
typedef __attribute__((ext_vector_type(4))) __bf16 bf16x4;

// ---------------------------------------------------------------------------
// shared MFMA tile step for the H GEMM (128x128, BK=32, 4 waves 2x2, 4x4 frags)
__device__ __forceinline__ void mfma_tile(const __bf16* As, const __bf16* Bs,
                                          int wm, int wn, int quad, int lr,
                                          f32x4 acc[4][4]) {
  bf16x8 a[4], b[4];
  const bf16x8* Ap = (const bf16x8*)As;
  const bf16x8* Bp = (const bf16x8*)Bs;
#pragma unroll
  for (int i = 0; i < 4; ++i) {
    a[i] = Ap[(wm * 64 + i * 16 + lr) * 4 + quad];
    b[i] = Bp[(wn * 64 + i * 16 + lr) * 4 + quad];
  }
#pragma unroll
  for (int mi = 0; mi < 4; ++mi)
#pragma unroll
    for (int ni = 0; ni < 4; ++ni)
      acc[mi][ni] = __builtin_amdgcn_mfma_f32_16x16x32_bf16(
          a[mi], b[ni], acc[mi][ni], 0, 0, 0);
}

// ---------------------------------------------------------------------------
// prep: weights-only precompute.
//   blocks [0, 64):   H = Wk @ Wq^T  [1024x1024] bf16 (128x128 tiles, K=256)
//   blocks [64, 68):  kb = Wk @ bq   [1024] fp32
__global__ __launch_bounds__(256) void prep_kernel(
    const float* __restrict__ Wq, const float* __restrict__ bq,
    const float* __restrict__ Wk, __bf16* __restrict__ H,
    float* __restrict__ kb) {
  __shared__ __align__(16) __bf16 As[128 * 32];
  __shared__ __align__(16) __bf16 Bs[128 * 32];
  const int bid = blockIdx.x;
  const int tid = threadIdx.x;
  if (bid < 64) {
    // H[m][n] = sum_j Wk[m][j] * Wq[n][j], m,n in 1024, j in 256
    const int mt = bid >> 3, nt = bid & 7;
    const int lane = tid & 63;
    const int wv = tid >> 6;
    const int quad = lane >> 4, lr = lane & 15;
    const int wm = wv >> 1, wn = wv & 1;
    const int r0 = tid >> 2, p0 = tid & 3;
    const float* ga0 = Wk + (size_t)(mt * 128 + r0) * MID_ + p0 * 8;
    const float* ga1 = ga0 + (size_t)64 * MID_;
    const float* gb0 = Wq + (size_t)(nt * 128 + r0) * MID_ + p0 * 8;
    const float* gb1 = gb0 + (size_t)64 * MID_;
    f32x4 acc[4][4] = {};
    for (int it = 0; it < 8; ++it) {
      const f32x4 a0 = *(const f32x4*)ga0, a1 = *(const f32x4*)(ga0 + 4);
      const f32x4 a2 = *(const f32x4*)ga1, a3 = *(const f32x4*)(ga1 + 4);
      const f32x4 b0 = *(const f32x4*)gb0, b1 = *(const f32x4*)(gb0 + 4);
      const f32x4 b2 = *(const f32x4*)gb1, b3 = *(const f32x4*)(gb1 + 4);
      ga0 += 32; ga1 += 32; gb0 += 32; gb1 += 32;
      bf16x8 ca0, ca1, cb0, cb1;
#pragma unroll
      for (int j = 0; j < 4; ++j) {
        ca0[j] = (__bf16)a0[j]; ca0[4 + j] = (__bf16)a1[j];
        ca1[j] = (__bf16)a2[j]; ca1[4 + j] = (__bf16)a3[j];
        cb0[j] = (__bf16)b0[j]; cb0[4 + j] = (__bf16)b1[j];
        cb1[j] = (__bf16)b2[j]; cb1[4 + j] = (__bf16)b3[j];
      }
      *(bf16x8*)(As + (size_t)tid * 8) = ca0;
      *(bf16x8*)(As + (size_t)(tid + 256) * 8) = ca1;
      *(bf16x8*)(Bs + (size_t)tid * 8) = cb0;
      *(bf16x8*)(Bs + (size_t)(tid + 256) * 8) = cb1;
      __syncthreads();
      mfma_tile(As, Bs, wm, wn, quad, lr, acc);
      __syncthreads();
    }
    const int colb = nt * 128 + wn * 64;
    const int rowb = mt * 128 + wm * 64 + quad * 4;
#pragma unroll
    for (int ni = 0; ni < 4; ++ni) {
      const int col = colb + ni * 16 + lr;
#pragma unroll
      for (int mi = 0; mi < 4; ++mi) {
        const int row = rowb + mi * 16;
#pragma unroll
        for (int r = 0; r < 4; ++r)
          H[(size_t)(row + r) * C_ + col] = (__bf16)acc[mi][ni][r];
      }
    }
  } else {
    __shared__ float bqs[256];
    bqs[tid] = bq[tid];
    __syncthreads();
    const int n = (bid - 64) * 256 + tid;
    const float* row = Wk + (size_t)n * MID_;
    float s = 0.f;
#pragma unroll 4
    for (int j = 0; j < 256; ++j) s += row[j] * bqs[j];
    kb[n] = s;
  }
}

// ---------------------------------------------------------------------------
// fused: per 32-pair tile (288 blocks x 1024 threads, 16 waves, 1 block/CU):
//   A: pool 2x2 windows from img -> bf16 LDS A-tile, stage kb
//   B: u = pooled @ H^T  (M=32, N=1024 split 16 waves x 64 cols, K=1024;
//      b-frags stream global->reg from L2-resident H, explicit ping-pong
//      double-buffer, fully-unrolled K loop, NO barriers)
//   C: u (fp32, +kb) -> LDS (overwrites pooled region after barrier)
//   D: logits u.v_w, softmax over 4 windows, out = pooled + sum a_w v_w
__global__ __launch_bounds__(1024, 4) void fused_kernel(
    const __bf16* __restrict__ H, const float* __restrict__ kb,
    const float* __restrict__ img, float* __restrict__ out) {
  __shared__ __align__(16) char ubuf[MP * UST * 4];  // 132,608 B union
  __shared__ float kbs[C_];
  __bf16* pool_s = (__bf16*)ubuf;  // [MP][PST] bf16 (phases A,B)
  float* u_s = (float*)ubuf;       // [MP][UST] fp32 (phases C,D)

  const int tid = threadIdx.x;
  const int bid = blockIdx.x;
  const int lane = tid & 63;
  const int wv = tid >> 6;              // 0..15
  const int quad = lane >> 4, lr = lane & 15;

  // pair mapping (phases A and D): 32 threads per pair
  const int p = tid >> 5;               // 0..31
  const int lp = tid & 31;
  const int gp = bid * MP + p;
  const int t = gp / P_;
  const int pp = gp - t * P_;
  const int wy = pp / 12, wx = pp - wy * 12;
  const float* base = img + ((size_t)t * 576 + 48 * wy + 2 * wx) * C_;

  // ---- Phase A: pool windows -> LDS bf16, stage kb -------------------------
#pragma unroll
  for (int j = 0; j < 8; ++j) {
    const int c = lp * 4 + j * 128;
    f32x4 s = *(const f32x4*)(base + c);
    s += *(const f32x4*)(base + C_ + c);
    s += *(const f32x4*)(base + 24 * C_ + c);
    s += *(const f32x4*)(base + 25 * C_ + c);
    s *= 0.25f;
    bf16x4 pv;
#pragma unroll
    for (int q = 0; q < 4; ++q) pv[q] = (__bf16)s[q];
    *(bf16x4*)(pool_s + p * PST + c) = pv;
  }
  if (tid < 256) *(f32x4*)(kbs + tid * 4) = *(const f32x4*)(kb + tid * 4);
  __syncthreads();

  // ---- Phase B: barrier-free GEMM, u = pooled @ H^T ------------------------
  // wave wv owns u cols [wv*64, wv*64+64); 2 M-frags x 4 N-frags.
  f32x4 acc[2][4] = {};
  const __bf16* ap0 = pool_s + lr * PST + quad * 8;
  const __bf16* ap1 = pool_s + (16 + lr) * PST + quad * 8;
  const __bf16* hp0 = H + (size_t)(wv * 64 + lr) * C_ + quad * 8;
  const __bf16* hp1 = hp0 + (size_t)16 * C_;
  const __bf16* hp2 = hp0 + (size_t)32 * C_;
  const __bf16* hp3 = hp0 + (size_t)48 * C_;

  bf16x8 bA0, bA1, bA2, bA3, bB0, bB1, bB2, bB3;
  bA0 = *(const bf16x8*)(hp0);
  bA1 = *(const bf16x8*)(hp1);
  bA2 = *(const bf16x8*)(hp2);
  bA3 = *(const bf16x8*)(hp3);
#pragma unroll
  for (int it = 0; it < 32; it += 2) {
    // prefetch K-step it+1 into B-bank (imm offsets, no addr VALU)
    bB0 = *(const bf16x8*)(hp0 + (it + 1) * 32);
    bB1 = *(const bf16x8*)(hp1 + (it + 1) * 32);
    bB2 = *(const bf16x8*)(hp2 + (it + 1) * 32);
    bB3 = *(const bf16x8*)(hp3 + (it + 1) * 32);
    {
      const bf16x8 a0 = *(const bf16x8*)(ap0 + it * 32);
      const bf16x8 a1 = *(const bf16x8*)(ap1 + it * 32);
      acc[0][0] = __builtin_amdgcn_mfma_f32_16x16x32_bf16(a0, bA0, acc[0][0], 0, 0, 0);
      acc[1][0] = __builtin_amdgcn_mfma_f32_16x16x32_bf16(a1, bA0, acc[1][0], 0, 0, 0);
      acc[0][1] = __builtin_amdgcn_mfma_f32_16x16x32_bf16(a0, bA1, acc[0][1], 0, 0, 0);
      acc[1][1] = __builtin_amdgcn_mfma_f32_16x16x32_bf16(a1, bA1, acc[1][1], 0, 0, 0);
      acc[0][2] = __builtin_amdgcn_mfma_f32_16x16x32_bf16(a0, bA2, acc[0][2], 0, 0, 0);
      acc[1][2] = __builtin_amdgcn_mfma_f32_16x16x32_bf16(a1, bA2, acc[1][2], 0, 0, 0);
      acc[0][3] = __builtin_amdgcn_mfma_f32_16x16x32_bf16(a0, bA3, acc[0][3], 0, 0, 0);
      acc[1][3] = __builtin_amdgcn_mfma_f32_16x16x32_bf16(a1, bA3, acc[1][3], 0, 0, 0);
    }
    if (it + 2 < 32) {  // prefetch K-step it+2 into A-bank
      bA0 = *(const bf16x8*)(hp0 + (it + 2) * 32);
      bA1 = *(const bf16x8*)(hp1 + (it + 2) * 32);
      bA2 = *(const bf16x8*)(hp2 + (it + 2) * 32);
      bA3 = *(const bf16x8*)(hp3 + (it + 2) * 32);
    }
    {
      const bf16x8 a0 = *(const bf16x8*)(ap0 + (it + 1) * 32);
      const bf16x8 a1 = *(const bf16x8*)(ap1 + (it + 1) * 32);
      acc[0][0] = __builtin_amdgcn_mfma_f32_16x16x32_bf16(a0, bB0, acc[0][0], 0, 0, 0);
      acc[1][0] = __builtin_amdgcn_mfma_f32_16x16x32_bf16(a1, bB0, acc[1][0], 0, 0, 0);
      acc[0][1] = __builtin_amdgcn_mfma_f32_16x16x32_bf16(a0, bB1, acc[0][1], 0, 0, 0);
      acc[1][1] = __builtin_amdgcn_mfma_f32_16x16x32_bf16(a1, bB1, acc[1][1], 0, 0, 0);
      acc[0][2] = __builtin_amdgcn_mfma_f32_16x16x32_bf16(a0, bB2, acc[0][2], 0, 0, 0);
      acc[1][2] = __builtin_amdgcn_mfma_f32_16x16x32_bf16(a1, bB2, acc[1][2], 0, 0, 0);
      acc[0][3] = __builtin_amdgcn_mfma_f32_16x16x32_bf16(a0, bB3, acc[0][3], 0, 0, 0);
      acc[1][3] = __builtin_amdgcn_mfma_f32_16x16x32_bf16(a1, bB3, acc[1][3], 0, 0, 0);
    }
  }
  __syncthreads();  // all A-tile reads done before overwrite

  // ---- Phase C: u (fp32, +kb) into LDS ------------------------------------
#pragma unroll
  for (int n = 0; n < 4; ++n) {
    const int col = wv * 64 + n * 16 + lr;
    const float kv = kbs[col];
#pragma unroll
    for (int mi = 0; mi < 2; ++mi)
#pragma unroll
      for (int r = 0; r < 4; ++r)
        u_s[(mi * 16 + quad * 4 + r) * UST + col] = acc[mi][n][r] + kv;
  }
  __syncthreads();

  // ---- Phase D: logits + softmax + output (32 lanes per pair) -------------
  float pd0 = 0.f, pd1 = 0.f, pd2 = 0.f, pd3 = 0.f;
  for (int j = 0; j < 8; ++j) {
    const int c = lp * 4 + j * 128;
    const f32x4 u4 = *(const f32x4*)(u_s + p * UST + c);
    const f32x4 v0 = *(const f32x4*)(base + c);
    const f32x4 v1 = *(const f32x4*)(base + C_ + c);
    const f32x4 v2 = *(const f32x4*)(base + 24 * C_ + c);
    const f32x4 v3 = *(const f32x4*)(base + 25 * C_ + c);
#pragma unroll
    for (int q = 0; q < 4; ++q) {
      pd0 += u4[q] * v0[q];
      pd1 += u4[q] * v1[q];
      pd2 += u4[q] * v2[q];
      pd3 += u4[q] * v3[q];
    }
  }
#pragma unroll
  for (int m = 16; m >= 1; m >>= 1) {
    pd0 += __shfl_xor(pd0, m, 32);
    pd1 += __shfl_xor(pd1, m, 32);
    pd2 += __shfl_xor(pd2, m, 32);
    pd3 += __shfl_xor(pd3, m, 32);
  }
  const float l0 = pd0 * 0.0625f, l1 = pd1 * 0.0625f;
  const float l2 = pd2 * 0.0625f, l3 = pd3 * 0.0625f;
  const float mx = fmaxf(fmaxf(l0, l1), fmaxf(l2, l3));
  const float e0 = __expf(l0 - mx), e1 = __expf(l1 - mx);
  const float e2 = __expf(l2 - mx), e3 = __expf(l3 - mx);
  const float inv = 1.f / (e0 + e1 + e2 + e3);
  const float a0 = e0 * inv + 0.25f, a1 = e1 * inv + 0.25f;
  const float a2 = e2 * inv + 0.25f, a3 = e3 * inv + 0.25f;
  float* op = out + (size_t)gp * C_;
  for (int j = 0; j < 8; ++j) {
    const int c = lp * 4 + j * 128;
    const f32x4 v0 = *(const f32x4*)(base + c);
    const f32x4 v1 = *(const f32x4*)(base + C_ + c);
    const f32x4 v2 = *(const f32x4*)(base + 24 * C_ + c);
    const f32x4 v3 = *(const f32x4*)(base + 25 * C_ + c);
    f32x4 o = a0 * v0 + a1 * v1 + a2 * v2 + a3 * v3;
    *(f32x4*)(op + c) = o;
  }
}

// ---------------------------------------------------------------------------
extern "C" void kernel_launch(void* const* d_in, const int* in_sizes, int n_in,
                              void* d_out, int out_size, void* d_ws,
                              size_t ws_size, hipStream_t stream) {
  const float* img = (const float*)d_in[0];
  const float* Wq = (const float*)d_in[1];
  const float* bq = (const float*)d_in[2];
  const float* Wk = (const float*)d_in[3];
  const float* bk = (const float*)d_in[4];  // constant under softmax -> unused
  (void)bk;
  float* out = (float*)d_out;

  // workspace layout (~2.1 MB)
  char* ws = (char*)d_ws;
  __bf16* H = (__bf16*)ws;                 // 1024*1024*2 = 2,097,152
  float* kb = (float*)(ws + 2097152);      // 1024*4      =     4,096

  // 1) H = Wk@Wq^T (bf16), kb = Wk@bq   (weights only, tiny)
  prep_kernel<<<68, 256, 0, stream>>>(Wq, bq, Wk, H, kb);
  // 2) fully fused: pool -> u = pooled@H^T + kb -> softmax -> output
  fused_kernel<<<NPAIR / MP, 1024, 0, stream>>>(H, kb, img, out);
}

// Round 3
// 317.546 us; speedup vs baseline: 1.3878x; 1.2617x over previous
//
#include <hip/hip_runtime.h>

// Problem constants
#define T_ 64
#define P_ 144          // 12*12 windows per frame
#define NPAIR 9216      // T_*P_
#define C_ 1024
#define MID_ 256

#define MP1 36          // pairs per pool_gemm block -> 9216/36 = 256 blocks
#define PST 1032        // bf16 pool LDS row stride (2064 B -> b128 reads at floor)

typedef __attribute__((ext_vector_type(4))) float f32x4;
typedef __attribute__((ext_vector_type(8))) __bf16 bf16x8;
typedef __attribute__((ext_vector_type(4))) __bf16 bf16x4;

__device__ __forceinline__ void async_copy16(const void* g, void* l) {
  __builtin_amdgcn_global_load_lds(
      (const __attribute__((address_space(1))) unsigned int*)g,
      (__attribute__((address_space(3))) unsigned int*)l, 16, 0, 0);
}

// ---------------------------------------------------------------------------
// shared MFMA tile step for the H GEMM (128x128, BK=32, 4 waves 2x2, 4x4 frags)
__device__ __forceinline__ void mfma_tile(const __bf16* As, const __bf16* Bs,
                                          int wm, int wn, int quad, int lr,
                                          f32x4 acc[4][4]) {
  bf16x8 a[4], b[4];
  const bf16x8* Ap = (const bf16x8*)As;
  const bf16x8* Bp = (const bf16x8*)Bs;
#pragma unroll
  for (int i = 0; i < 4; ++i) {
    a[i] = Ap[(wm * 64 + i * 16 + lr) * 4 + quad];
    b[i] = Bp[(wn * 64 + i * 16 + lr) * 4 + quad];
  }
#pragma unroll
  for (int mi = 0; mi < 4; ++mi)
#pragma unroll
    for (int ni = 0; ni < 4; ++ni)
      acc[mi][ni] = __builtin_amdgcn_mfma_f32_16x16x32_bf16(
          a[mi], b[ni], acc[mi][ni], 0, 0, 0);
}

// ---------------------------------------------------------------------------
// prep: weights-only precompute.
//   blocks [0, 64):   H = Wk @ Wq^T  [1024x1024] bf16 (128x128 tiles, K=256)
//   blocks [64, 68):  kb = Wk @ bq   [1024] fp32
__global__ __launch_bounds__(256) void prep_kernel(
    const float* __restrict__ Wq, const float* __restrict__ bq,
    const float* __restrict__ Wk, __bf16* __restrict__ H,
    float* __restrict__ kb) {
  __shared__ __align__(16) __bf16 As[128 * 32];
  __shared__ __align__(16) __bf16 Bs[128 * 32];
  const int bid = blockIdx.x;
  const int tid = threadIdx.x;
  if (bid < 64) {
    const int mt = bid >> 3, nt = bid & 7;
    const int lane = tid & 63;
    const int wv = tid >> 6;
    const int quad = lane >> 4, lr = lane & 15;
    const int wm = wv >> 1, wn = wv & 1;
    const int r0 = tid >> 2, p0 = tid & 3;
    const float* ga0 = Wk + (size_t)(mt * 128 + r0) * MID_ + p0 * 8;
    const float* ga1 = ga0 + (size_t)64 * MID_;
    const float* gb0 = Wq + (size_t)(nt * 128 + r0) * MID_ + p0 * 8;
    const float* gb1 = gb0 + (size_t)64 * MID_;
    f32x4 acc[4][4] = {};
    for (int it = 0; it < 8; ++it) {
      const f32x4 a0 = *(const f32x4*)ga0, a1 = *(const f32x4*)(ga0 + 4);
      const f32x4 a2 = *(const f32x4*)ga1, a3 = *(const f32x4*)(ga1 + 4);
      const f32x4 b0 = *(const f32x4*)gb0, b1 = *(const f32x4*)(gb0 + 4);
      const f32x4 b2 = *(const f32x4*)gb1, b3 = *(const f32x4*)(gb1 + 4);
      ga0 += 32; ga1 += 32; gb0 += 32; gb1 += 32;
      bf16x8 ca0, ca1, cb0, cb1;
#pragma unroll
      for (int j = 0; j < 4; ++j) {
        ca0[j] = (__bf16)a0[j]; ca0[4 + j] = (__bf16)a1[j];
        ca1[j] = (__bf16)a2[j]; ca1[4 + j] = (__bf16)a3[j];
        cb0[j] = (__bf16)b0[j]; cb0[4 + j] = (__bf16)b1[j];
        cb1[j] = (__bf16)b2[j]; cb1[4 + j] = (__bf16)b3[j];
      }
      *(bf16x8*)(As + (size_t)tid * 8) = ca0;
      *(bf16x8*)(As + (size_t)(tid + 256) * 8) = ca1;
      *(bf16x8*)(Bs + (size_t)tid * 8) = cb0;
      *(bf16x8*)(Bs + (size_t)(tid + 256) * 8) = cb1;
      __syncthreads();
      mfma_tile(As, Bs, wm, wn, quad, lr, acc);
      __syncthreads();
    }
    const int colb = nt * 128 + wn * 64;
    const int rowb = mt * 128 + wm * 64 + quad * 4;
#pragma unroll
    for (int ni = 0; ni < 4; ++ni) {
      const int col = colb + ni * 16 + lr;
#pragma unroll
      for (int mi = 0; mi < 4; ++mi) {
        const int row = rowb + mi * 16;
#pragma unroll
        for (int r = 0; r < 4; ++r)
          H[(size_t)(row + r) * C_ + col] = (__bf16)acc[mi][ni][r];
      }
    }
  } else {
    __shared__ float bqs[256];
    bqs[tid] = bq[tid];
    __syncthreads();
    const int n = (bid - 64) * 256 + tid;
    const float* row = Wk + (size_t)n * MID_;
    float s = 0.f;
#pragma unroll 4
    for (int j = 0; j < 256; ++j) s += row[j] * bqs[j];
    kb[n] = s;
  }
}

// ---------------------------------------------------------------------------
// pool_gemm: 256 blocks x 1024 threads (16 waves, 1 block/CU).
//   A: pool 36 pairs' 2x2 windows from img -> bf16 LDS [36][PST]
//   B: u = pooled @ H^T  (M-tile 48 rows (36 used), N=1024: wave wv owns cols
//      [wv*64, +64), K=1024 in 32 steps; per step stage H[1024][32k] (64 KB)
//      into LDS via global_load_lds w16, barrier, 3x4 MFMAs/wave, barrier)
//   C: u = acc + kb -> bf16 via LDS (reuses pool region) -> coalesced stores
__global__ __launch_bounds__(1024, 4) void pool_gemm_kernel(
    const __bf16* __restrict__ H, const float* __restrict__ kb,
    const float* __restrict__ img, __bf16* __restrict__ U) {
  __shared__ __align__(16) __bf16 pool_s[MP1 * PST];   // 74,304 B
  __shared__ __align__(16) __bf16 hs[1024 * 32];       // 65,536 B
  __shared__ float kbs[C_];                            //  4,096 B
  const int tid = threadIdx.x;
  const int bid = blockIdx.x;
  const int lane = tid & 63;
  const int wv = tid >> 6;              // 0..15
  const int quad = lane >> 4, lr = lane & 15;

  // ---- Phase A: pool -> LDS bf16 ------------------------------------------
#pragma unroll
  for (int s = 0; s < 9; ++s) {
    const int cid = tid + s * 1024;     // 0..9215 = 36 pairs * 256 chunks
    const int p = cid >> 8;
    const int c = (cid & 255) * 4;
    const int gp = bid * MP1 + p;
    const int t = gp / P_;
    const int pp = gp - t * P_;
    const int wy = pp / 12, wx = pp - wy * 12;
    const float* base = img + ((size_t)t * 576 + 48 * wy + 2 * wx) * C_;
    f32x4 sm = *(const f32x4*)(base + c);
    sm += *(const f32x4*)(base + C_ + c);
    sm += *(const f32x4*)(base + 24 * C_ + c);
    sm += *(const f32x4*)(base + 25 * C_ + c);
    sm *= 0.25f;
    bf16x4 pv;
#pragma unroll
    for (int q = 0; q < 4; ++q) pv[q] = (__bf16)sm[q];
    *(bf16x4*)(pool_s + p * PST + c) = pv;
  }
  if (tid < 256) *(f32x4*)(kbs + tid * 4) = *(const f32x4*)(kb + tid * 4);

  // ---- Phase B: u = pooled @ H^T (m97-style LDS-staged K loop) ------------
  f32x4 acc[3][4] = {};
  const int hrow = tid >> 2;            // 0..255
  const __bf16* hsrc = H + (size_t)hrow * C_ + (tid & 3) * 8;
  char* hdst = (char*)hs + tid * 16;    // = wave-uniform base + lane*16

  for (int it = 0; it < 32; ++it) {
    const __bf16* src = hsrc + it * 32;
#pragma unroll
    for (int i = 0; i < 4; ++i)
      async_copy16(src + (size_t)i * 256 * C_, hdst + i * 16384);
    __syncthreads();   // copies landed (+ phase A writes on first iter)
    bf16x8 a[3], b[4];
#pragma unroll
    for (int mi = 0; mi < 3; ++mi)
      a[mi] = *(const bf16x8*)(pool_s + (mi * 16 + lr) * PST + it * 32 + quad * 8);
#pragma unroll
    for (int j = 0; j < 4; ++j)
      b[j] = *(const bf16x8*)(hs + (wv * 64 + j * 16 + lr) * 32 + quad * 8);
#pragma unroll
    for (int mi = 0; mi < 3; ++mi)
#pragma unroll
      for (int j = 0; j < 4; ++j)
        acc[mi][j] = __builtin_amdgcn_mfma_f32_16x16x32_bf16(
            a[mi], b[j], acc[mi][j], 0, 0, 0);
    __syncthreads();   // hs reads done before next overwrite
  }

  // ---- Phase C: u = acc + kb -> bf16 via pool LDS -> coalesced store ------
#pragma unroll
  for (int n = 0; n < 4; ++n) {
    const int col = wv * 64 + n * 16 + lr;
    const float kv = kbs[col];
#pragma unroll
    for (int mi = 0; mi < 3; ++mi) {
      const int rowb = mi * 16 + quad * 4;
#pragma unroll
      for (int r = 0; r < 4; ++r) {
        const int rr = rowb + r;
        if (rr < MP1) pool_s[rr * PST + col] = (__bf16)(acc[mi][n][r] + kv);
      }
    }
  }
  __syncthreads();
  for (int i = tid; i < MP1 * 128; i += 1024) {
    const int r = i >> 7, c8 = (i & 127) * 8;
    *(bf16x8*)(U + ((size_t)bid * MP1 + r) * C_ + c8) =
        *(const bf16x8*)(pool_s + r * PST + c8);
  }
}

// ---------------------------------------------------------------------------
// attn: per-(t,p): logit_w = (u·v_w)*scale, softmax over 4,
// out = pooled + sum attn*window; v from fp32 img (L3-warm), u bf16.
__global__ void attn_out_kernel(const __bf16* __restrict__ U,
                                const float* __restrict__ img,
                                float* __restrict__ out) {
  const int pair = blockIdx.x;
  const int tid = threadIdx.x;
  const int wv = tid >> 6, lane = tid & 63;
  __shared__ float red[4][4];

  const int t = pair / P_;
  const int pp = pair - t * P_;
  const int wy = pp / 12, wx = pp - wy * 12;
  const float* base = img + ((size_t)t * 576 + 48 * wy + 2 * wx) * C_;
  const int c = tid * 4;
  f32x4 v0 = *(const f32x4*)(base + c);
  f32x4 v1 = *(const f32x4*)(base + (size_t)1 * C_ + c);
  f32x4 v2 = *(const f32x4*)(base + (size_t)24 * C_ + c);
  f32x4 v3 = *(const f32x4*)(base + (size_t)25 * C_ + c);
  const bf16x4 ub = *(const bf16x4*)(U + (size_t)pair * C_ + c);
  f32x4 u4;
#pragma unroll
  for (int j = 0; j < 4; ++j) u4[j] = (float)ub[j];

  float pd[4];
  pd[0] = u4[0] * v0[0] + u4[1] * v0[1] + u4[2] * v0[2] + u4[3] * v0[3];
  pd[1] = u4[0] * v1[0] + u4[1] * v1[1] + u4[2] * v1[2] + u4[3] * v1[3];
  pd[2] = u4[0] * v2[0] + u4[1] * v2[1] + u4[2] * v2[2] + u4[3] * v2[3];
  pd[3] = u4[0] * v3[0] + u4[1] * v3[1] + u4[2] * v3[2] + u4[3] * v3[3];

#pragma unroll
  for (int w = 0; w < 4; ++w) {
    float p = pd[w];
    p += __shfl_down(p, 32);
    p += __shfl_down(p, 16);
    p += __shfl_down(p, 8);
    p += __shfl_down(p, 4);
    p += __shfl_down(p, 2);
    p += __shfl_down(p, 1);
    if (lane == 0) red[w][wv] = p;
  }
  __syncthreads();
  float lg[4];
  float mx = -1e30f;
#pragma unroll
  for (int w = 0; w < 4; ++w) {
    lg[w] = (red[w][0] + red[w][1] + red[w][2] + red[w][3]) * 0.0625f;
    mx = fmaxf(mx, lg[w]);
  }
  float att[4];
  float ssum = 0.f;
#pragma unroll
  for (int w = 0; w < 4; ++w) {
    att[w] = __expf(lg[w] - mx);
    ssum += att[w];
  }
  const float inv = 1.f / ssum;
  const float a0 = att[0] * inv + 0.25f, a1 = att[1] * inv + 0.25f;
  const float a2 = att[2] * inv + 0.25f, a3 = att[3] * inv + 0.25f;

  f32x4 o = a0 * v0 + a1 * v1 + a2 * v2 + a3 * v3;
  *(f32x4*)(out + (size_t)pair * C_ + c) = o;
}

// ---------------------------------------------------------------------------
extern "C" void kernel_launch(void* const* d_in, const int* in_sizes, int n_in,
                              void* d_out, int out_size, void* d_ws,
                              size_t ws_size, hipStream_t stream) {
  const float* img = (const float*)d_in[0];
  const float* Wq = (const float*)d_in[1];
  const float* bq = (const float*)d_in[2];
  const float* Wk = (const float*)d_in[3];
  const float* bk = (const float*)d_in[4];  // constant under softmax -> unused
  (void)bk;
  float* out = (float*)d_out;

  // workspace layout (~21 MB)
  char* ws = (char*)d_ws;
  __bf16* H = (__bf16*)ws;                  // 1024*1024*2 = 2,097,152
  float* kb = (float*)(ws + 2097152);       // 1024*4      =     4,096
  __bf16* U = (__bf16*)(ws + 2101248);      // 9216*1024*2 = 18,874,368

  // 1) H = Wk@Wq^T (bf16), kb = Wk@bq   (weights only, tiny)
  prep_kernel<<<68, 256, 0, stream>>>(Wq, bq, Wk, H, kb);
  // 2) pool + u = pooled@H^T + kb  (LDS-staged H, global_load_lds w16)
  pool_gemm_kernel<<<256, 1024, 0, stream>>>(H, kb, img, U);
  // 3) logits from U and img windows, softmax, weighted output
  attn_out_kernel<<<NPAIR, 256, 0, stream>>>(U, img, out);
}

// Round 5
// 286.707 us; speedup vs baseline: 1.5371x; 1.1076x over previous
//
#include <hip/hip_runtime.h>

// Problem constants
#define T_ 64
#define P_ 144          // 12*12 windows per frame
#define NPAIR 9216      // T_*P_
#define C_ 1024
#define MID_ 256

typedef __attribute__((ext_vector_type(4))) float f32x4;
typedef __attribute__((ext_vector_type(8))) __bf16 bf16x8;
typedef __attribute__((ext_vector_type(4))) __bf16 bf16x4;

__device__ __forceinline__ void async_copy16(const void* g, void* l) {
  __builtin_amdgcn_global_load_lds(
      (const __attribute__((address_space(1))) unsigned int*)g,
      (__attribute__((address_space(3))) unsigned int*)l, 16, 0, 0);
}

// ---------------------------------------------------------------------------
// shared MFMA tile step (128x128 tile, BK=32, 4 waves 2x2, 4x4 frags)
__device__ __forceinline__ void mfma_tile(const __bf16* As, const __bf16* Bs,
                                          int wm, int wn, int quad, int lr,
                                          f32x4 acc[4][4]) {
  bf16x8 a[4], b[4];
  const bf16x8* Ap = (const bf16x8*)As;
  const bf16x8* Bp = (const bf16x8*)Bs;
#pragma unroll
  for (int i = 0; i < 4; ++i) {
    a[i] = Ap[(wm * 64 + i * 16 + lr) * 4 + quad];
    b[i] = Bp[(wn * 64 + i * 16 + lr) * 4 + quad];
  }
#pragma unroll
  for (int mi = 0; mi < 4; ++mi)
#pragma unroll
    for (int ni = 0; ni < 4; ++ni)
      acc[mi][ni] = __builtin_amdgcn_mfma_f32_16x16x32_bf16(
          a[mi], b[ni], acc[mi][ni], 0, 0, 0);
}

// ---------------------------------------------------------------------------
// K1: blocks [0, NPAIR): mean-pool 2x2 windows -> pooled bf16
//     blocks [NPAIR, +64): Wq [1024][256] -> Wqt bf16 [256][1024] (transpose)
//     blocks [NPAIR+64, +32): Wk [1024][256] -> Wkb bf16 (cast only)
__global__ __launch_bounds__(256) void pool_prep_kernel(
    const float* __restrict__ img, const float* __restrict__ Wq,
    const float* __restrict__ Wk, __bf16* __restrict__ poolb,
    __bf16* __restrict__ Wqt, __bf16* __restrict__ Wkb) {
  const int bid = blockIdx.x;
  const int tid = threadIdx.x;
  if (bid < NPAIR) {
    const int t = bid / P_;
    const int p = bid - t * P_;
    const int wy = p / 12, wx = p - wy * 12;
    const int c = tid * 4;
    const float* base = img + ((size_t)t * 576 + 48 * wy + 2 * wx) * C_;
    f32x4 s = *(const f32x4*)(base + c);
    s += *(const f32x4*)(base + (size_t)1 * C_ + c);
    s += *(const f32x4*)(base + (size_t)24 * C_ + c);
    s += *(const f32x4*)(base + (size_t)25 * C_ + c);
    s *= 0.25f;
    bf16x4 pv;
#pragma unroll
    for (int j = 0; j < 4; ++j) pv[j] = (__bf16)s[j];
    *(bf16x4*)(poolb + (size_t)bid * C_ + c) = pv;
  } else if (bid < NPAIR + 64) {
    // transpose one 128c x 32d tile of Wq into Wqt
    const int b = bid - NPAIR;
    const int ct = b >> 3, dt = b & 7;
    __shared__ float tile[128][33];
    const int r = tid >> 3;             // 0..31
    const int c4 = (tid & 7) * 4;       // 0..28
#pragma unroll
    for (int s = 0; s < 4; ++s) {
      const int row = r + s * 32;       // c within tile
      const f32x4 v =
          *(const f32x4*)(Wq + (size_t)(ct * 128 + row) * MID_ + dt * 32 + c4);
      tile[row][c4 + 0] = v[0]; tile[row][c4 + 1] = v[1];
      tile[row][c4 + 2] = v[2]; tile[row][c4 + 3] = v[3];
    }
    __syncthreads();
    const int dd = tid >> 5;            // 0..7
    const int cc4 = (tid & 31) * 4;     // 0..124
#pragma unroll
    for (int s = 0; s < 4; ++s) {
      const int d = dd + s * 8;
      bf16x4 o;
#pragma unroll
      for (int j = 0; j < 4; ++j) o[j] = (__bf16)tile[cc4 + j][d];
      *(bf16x4*)(Wqt + (size_t)(dt * 32 + d) * C_ + ct * 128 + cc4) = o;
    }
  } else {
    // cast Wk -> bf16, layout preserved ([c][d] == B^T layout for GEMM2)
    const int b = bid - NPAIR - 64;
    const float* src = Wk + (size_t)b * 8192;
    __bf16* dst = Wkb + (size_t)b * 8192;
#pragma unroll
    for (int s = 0; s < 8; ++s) {
      const f32x4 v = *(const f32x4*)(src + tid * 4 + s * 1024);
      bf16x4 o;
#pragma unroll
      for (int j = 0; j < 4; ++j) o[j] = (__bf16)v[j];
      *(bf16x4*)(dst + tid * 4 + s * 1024) = o;
    }
  }
}

// ---------------------------------------------------------------------------
// K2: q = pooled @ Wqt^T + bq   (9216x256, K=1024) -> bf16
// m97 pattern: 128x128 tile, BK=32, global_load_lds width-16. grid 72x2.
__global__ __launch_bounds__(256) void gemm_q_kernel(
    const __bf16* __restrict__ A, const __bf16* __restrict__ Bt,
    const float* __restrict__ bias, __bf16* __restrict__ Q) {
  __shared__ __align__(16) __bf16 As[128 * 32];
  __shared__ __align__(16) __bf16 Bs[128 * 32];
  const int bid = blockIdx.x;
  const int mt = bid >> 1, nt = bid & 1;
  const int tid = threadIdx.x;
  const int lane = tid & 63;
  const int wv = tid >> 6;
  const int quad = lane >> 4, lr = lane & 15;
  const int wm = wv >> 1, wn = wv & 1;

  const int r0 = tid >> 2, p0 = tid & 3;
  const int wvb = (tid & ~63) * 16;
  const __bf16* ga0 = A + ((size_t)mt * 128 + r0) * (size_t)C_ + p0 * 8;
  const __bf16* ga1 = ga0 + (size_t)64 * C_;
  const __bf16* gb0 = Bt + ((size_t)nt * 128 + r0) * (size_t)C_ + p0 * 8;
  const __bf16* gb1 = gb0 + (size_t)64 * C_;
  char* AsB0 = (char*)As + wvb;
  char* AsB1 = (char*)As + 4096 + wvb;
  char* BsB0 = (char*)Bs + wvb;
  char* BsB1 = (char*)Bs + 4096 + wvb;

  f32x4 acc[4][4] = {};

  for (int it = 0; it < 32; ++it) {
    async_copy16(ga0, AsB0);
    async_copy16(ga1, AsB1);
    async_copy16(gb0, BsB0);
    async_copy16(gb1, BsB1);
    ga0 += 32; ga1 += 32; gb0 += 32; gb1 += 32;
    __syncthreads();
    mfma_tile(As, Bs, wm, wn, quad, lr, acc);
    __syncthreads();
  }

  const int colb = nt * 128 + wn * 64;
  const int rowb = mt * 128 + wm * 64 + quad * 4;
#pragma unroll
  for (int ni = 0; ni < 4; ++ni) {
    const int col = colb + ni * 16 + lr;
    const float bv = bias[col];
#pragma unroll
    for (int mi = 0; mi < 4; ++mi) {
      const int row = rowb + mi * 16;
#pragma unroll
      for (int r = 0; r < 4; ++r)
        Q[(size_t)(row + r) * MID_ + col] = (__bf16)(acc[mi][ni][r] + bv);
    }
  }
}

// ---------------------------------------------------------------------------
// K3: u = q @ Wkb^T   (9216x1024, K=256) -> bf16. grid 72x8 = 576 blocks.
__global__ __launch_bounds__(256) void gemm_u_kernel(
    const __bf16* __restrict__ A, const __bf16* __restrict__ Bt,
    __bf16* __restrict__ U) {
  __shared__ __align__(16) __bf16 As[128 * 32];
  __shared__ __align__(16) __bf16 Bs[128 * 32];
  const int bid = blockIdx.x;
  const int mt = bid >> 3, nt = bid & 7;
  const int tid = threadIdx.x;
  const int lane = tid & 63;
  const int wv = tid >> 6;
  const int quad = lane >> 4, lr = lane & 15;
  const int wm = wv >> 1, wn = wv & 1;

  const int r0 = tid >> 2, p0 = tid & 3;
  const int wvb = (tid & ~63) * 16;
  const __bf16* ga0 = A + ((size_t)mt * 128 + r0) * (size_t)MID_ + p0 * 8;
  const __bf16* ga1 = ga0 + (size_t)64 * MID_;
  const __bf16* gb0 = Bt + ((size_t)nt * 128 + r0) * (size_t)MID_ + p0 * 8;
  const __bf16* gb1 = gb0 + (size_t)64 * MID_;
  char* AsB0 = (char*)As + wvb;
  char* AsB1 = (char*)As + 4096 + wvb;
  char* BsB0 = (char*)Bs + wvb;
  char* BsB1 = (char*)Bs + 4096 + wvb;

  f32x4 acc[4][4] = {};

  for (int it = 0; it < 8; ++it) {
    async_copy16(ga0, AsB0);
    async_copy16(ga1, AsB1);
    async_copy16(gb0, BsB0);
    async_copy16(gb1, BsB1);
    ga0 += 32; ga1 += 32; gb0 += 32; gb1 += 32;
    __syncthreads();
    mfma_tile(As, Bs, wm, wn, quad, lr, acc);
    __syncthreads();
  }

  const int colb = nt * 128 + wn * 64;
  const int rowb = mt * 128 + wm * 64 + quad * 4;
#pragma unroll
  for (int ni = 0; ni < 4; ++ni) {
    const int col = colb + ni * 16 + lr;
#pragma unroll
    for (int mi = 0; mi < 4; ++mi) {
      const int row = rowb + mi * 16;
#pragma unroll
      for (int r = 0; r < 4; ++r)
        U[(size_t)(row + r) * C_ + col] = (__bf16)acc[mi][ni][r];
    }
  }
}

// ---------------------------------------------------------------------------
// K4: per-(t,p): logit_w = (u·v_w)*scale, softmax over 4,
// out = pooled + sum attn*window; v from fp32 img (L3-warm), u bf16.
__global__ void attn_out_kernel(const __bf16* __restrict__ U,
                                const float* __restrict__ img,
                                float* __restrict__ out) {
  const int pair = blockIdx.x;
  const int tid = threadIdx.x;
  const int wv = tid >> 6, lane = tid & 63;
  __shared__ float red[4][4];

  const int t = pair / P_;
  const int pp = pair - t * P_;
  const int wy = pp / 12, wx = pp - wy * 12;
  const float* base = img + ((size_t)t * 576 + 48 * wy + 2 * wx) * C_;
  const int c = tid * 4;
  f32x4 v0 = *(const f32x4*)(base + c);
  f32x4 v1 = *(const f32x4*)(base + (size_t)1 * C_ + c);
  f32x4 v2 = *(const f32x4*)(base + (size_t)24 * C_ + c);
  f32x4 v3 = *(const f32x4*)(base + (size_t)25 * C_ + c);
  const bf16x4 ub = *(const bf16x4*)(U + (size_t)pair * C_ + c);
  f32x4 u4;
#pragma unroll
  for (int j = 0; j < 4; ++j) u4[j] = (float)ub[j];

  float pd[4];
  pd[0] = u4[0] * v0[0] + u4[1] * v0[1] + u4[2] * v0[2] + u4[3] * v0[3];
  pd[1] = u4[0] * v1[0] + u4[1] * v1[1] + u4[2] * v1[2] + u4[3] * v1[3];
  pd[2] = u4[0] * v2[0] + u4[1] * v2[1] + u4[2] * v2[2] + u4[3] * v2[3];
  pd[3] = u4[0] * v3[0] + u4[1] * v3[1] + u4[2] * v3[2] + u4[3] * v3[3];

#pragma unroll
  for (int w = 0; w < 4; ++w) {
    float p = pd[w];
    p += __shfl_down(p, 32);
    p += __shfl_down(p, 16);
    p += __shfl_down(p, 8);
    p += __shfl_down(p, 4);
    p += __shfl_down(p, 2);
    p += __shfl_down(p, 1);
    if (lane == 0) red[w][wv] = p;
  }
  __syncthreads();
  float lg[4];
  float mx = -1e30f;
#pragma unroll
  for (int w = 0; w < 4; ++w) {
    lg[w] = (red[w][0] + red[w][1] + red[w][2] + red[w][3]) * 0.0625f;
    mx = fmaxf(mx, lg[w]);
  }
  float att[4];
  float ssum = 0.f;
#pragma unroll
  for (int w = 0; w < 4; ++w) {
    att[w] = __expf(lg[w] - mx);
    ssum += att[w];
  }
  const float inv = 1.f / ssum;
  const float a0 = att[0] * inv + 0.25f, a1 = att[1] * inv + 0.25f;
  const float a2 = att[2] * inv + 0.25f, a3 = att[3] * inv + 0.25f;

  f32x4 o = a0 * v0 + a1 * v1 + a2 * v2 + a3 * v3;
  *(f32x4*)(out + (size_t)pair * C_ + c) = o;
}

// ---------------------------------------------------------------------------
extern "C" void kernel_launch(void* const* d_in, const int* in_sizes, int n_in,
                              void* d_out, int out_size, void* d_ws,
                              size_t ws_size, hipStream_t stream) {
  const float* img = (const float*)d_in[0];
  const float* Wq = (const float*)d_in[1];
  const float* bq = (const float*)d_in[2];
  const float* Wk = (const float*)d_in[3];
  const float* bk = (const float*)d_in[4];  // constant under softmax -> unused
  (void)bk;
  float* out = (float*)d_out;

  // workspace layout (~43.5 MB)
  char* ws = (char*)d_ws;
  __bf16* poolb = (__bf16*)ws;               //  9216*1024*2 = 18,874,368
  __bf16* Wqt = (__bf16*)(ws + 18874368);    //   256*1024*2 =    524,288
  __bf16* Wkb = (__bf16*)(ws + 19398656);    //  1024*256*2  =    524,288
  __bf16* Qb  = (__bf16*)(ws + 19922944);    //  9216*256*2  =  4,718,592
  __bf16* U   = (__bf16*)(ws + 24641536);    //  9216*1024*2 = 18,874,368

  // 1) pool -> bf16; Wq transpose->bf16; Wk cast->bf16 (one launch)
  pool_prep_kernel<<<NPAIR + 96, 256, 0, stream>>>(img, Wq, Wk, poolb, Wqt, Wkb);
  // 2) q = pooled @ Wq + bq   (rank-256 factorization, half the FLOPs of H)
  gemm_q_kernel<<<144, 256, 0, stream>>>(poolb, Wqt, bq, Qb);
  // 3) u = q @ Wk^T           (q·bk drops under softmax)
  gemm_u_kernel<<<576, 256, 0, stream>>>(Qb, Wkb, U);
  // 4) logits from U and img windows, softmax, weighted output
  attn_out_kernel<<<NPAIR, 256, 0, stream>>>(U, img, out);
}